// Round 1
// baseline (246.895 us; speedup 1.0000x reference)
//
#include <hip/hip_runtime.h>

// HyperConv: y[b,o,t] = sum_{i<3} sum_{c<16} x[b,c,t+8-4i] * w_b[i*16+c][o]
// w_b = LeakyReLU(p[b]@W1 + b1) @ W2 + b2, reshaped [48][16].
//
// Memory-bound: x (134 MiB) + y (128 MiB) => ~44us floor at 6.3 TB/s.
// One block = one (batch, 1024-t chunk); block redundantly builds its
// 768-float weight tile in LDS (W2 is L2-resident, cost is negligible).

#define NB 32
#define IN_CH 16
#define OUT_CH 16
#define KW 3
#define DIL 4
#define COND 8
#define T_OUT 65536
#define PADT 8
#define XT (T_OUT + PADT)           // 65544, divisible by 8 -> float4 aligned
#define W2COLS (IN_CH * OUT_CH * KW) // 768
#define TPB 256
#define TPT 4                        // t-positions per thread
#define T_PER_BLOCK (TPB * TPT)      // 1024
#define BLOCKS_PER_B (T_OUT / T_PER_BLOCK) // 64

__global__ __launch_bounds__(TPB)
void hyperconv_kernel(const float* __restrict__ x,
                      const float* __restrict__ p,
                      const float* __restrict__ W1,
                      const float* __restrict__ b1,
                      const float* __restrict__ W2,
                      const float* __restrict__ b2,
                      float* __restrict__ y)
{
    __shared__ float h_lds[IN_CH];
    __shared__ float w_lds[W2COLS];  // [row=i*16+c][o], row-major, 3 KiB

    const int tid    = threadIdx.x;
    const int b      = blockIdx.x / BLOCKS_PER_B;
    const int tchunk = blockIdx.x % BLOCKS_PER_B;

    // ---- hypernetwork: h = LeakyReLU(p[b] @ W1 + b1) ----
    if (tid < IN_CH) {
        float acc = b1[tid];
#pragma unroll
        for (int j = 0; j < COND; ++j)
            acc += p[b * COND + j] * W1[j * IN_CH + tid];
        h_lds[tid] = acc > 0.f ? acc : 0.2f * acc;
    }
    __syncthreads();

    // ---- w = h @ W2 + b2 : 768 entries, 3 per thread ----
#pragma unroll
    for (int r = 0; r < 3; ++r) {
        const int n = tid * 3 + r;
        float acc = b2[n];
#pragma unroll
        for (int c = 0; c < IN_CH; ++c)
            acc += h_lds[c] * W2[c * W2COLS + n];
        w_lds[n] = acc;
    }
    __syncthreads();

    // ---- main conv: 4 consecutive t per thread, all 16 outputs ----
    const int t0 = tchunk * T_PER_BLOCK + tid * TPT;
    const float* xb = x + (size_t)b * IN_CH * XT + t0;

    float4 acc[OUT_CH];
#pragma unroll
    for (int o = 0; o < OUT_CH; ++o) acc[o] = make_float4(0.f, 0.f, 0.f, 0.f);

#pragma unroll
    for (int c = 0; c < IN_CH; ++c) {
        // taps: x index = t + 8 - 4*i ; i=2 -> +0, i=1 -> +4, i=0 -> +8
        const float4 a0 = *(const float4*)(xb + c * XT);      // i = 2
        const float4 a1 = *(const float4*)(xb + c * XT + 4);  // i = 1
        const float4 a2 = *(const float4*)(xb + c * XT + 8);  // i = 0
        const float4 vs[KW] = {a2, a1, a0};                   // indexed by i
#pragma unroll
        for (int i = 0; i < KW; ++i) {
            const float4 v = vs[i];
            const float* wrow = &w_lds[(i * IN_CH + c) * OUT_CH];
#pragma unroll
            for (int og = 0; og < 4; ++og) {
                const float4 wv = *(const float4*)(wrow + og * 4);
                float4* a = &acc[og * 4];
                a[0].x += v.x * wv.x; a[0].y += v.y * wv.x;
                a[0].z += v.z * wv.x; a[0].w += v.w * wv.x;
                a[1].x += v.x * wv.y; a[1].y += v.y * wv.y;
                a[1].z += v.z * wv.y; a[1].w += v.w * wv.y;
                a[2].x += v.x * wv.z; a[2].y += v.y * wv.z;
                a[2].z += v.z * wv.z; a[2].w += v.w * wv.z;
                a[3].x += v.x * wv.w; a[3].y += v.y * wv.w;
                a[3].z += v.z * wv.w; a[3].w += v.w * wv.w;
            }
        }
    }

    float* yb = y + (size_t)b * OUT_CH * T_OUT + t0;
#pragma unroll
    for (int o = 0; o < OUT_CH; ++o)
        *(float4*)(yb + o * T_OUT) = acc[o];
}

extern "C" void kernel_launch(void* const* d_in, const int* in_sizes, int n_in,
                              void* d_out, int out_size, void* d_ws, size_t ws_size,
                              hipStream_t stream) {
    const float* x  = (const float*)d_in[0];
    const float* p  = (const float*)d_in[1];
    const float* W1 = (const float*)d_in[2];
    const float* b1 = (const float*)d_in[3];
    const float* W2 = (const float*)d_in[4];
    const float* b2 = (const float*)d_in[5];
    float* y = (float*)d_out;

    dim3 grid(NB * BLOCKS_PER_B);   // 2048 blocks
    dim3 block(TPB);
    hyperconv_kernel<<<grid, block, 0, stream>>>(x, p, W1, b1, W2, b2, y);
}